// Round 1
// 1361.445 us; speedup vs baseline: 1.0399x; 1.0399x over previous
//
#include <hip/hip_runtime.h>
#include <hip/hip_bf16.h>

typedef __bf16 bf16x8 __attribute__((ext_vector_type(8)));
typedef float floatx4 __attribute__((ext_vector_type(4)));
typedef unsigned short ushort_t;
typedef ushort_t ushort8 __attribute__((ext_vector_type(8)));

#define KD 768   // d_model = inner K of both GEMMs

// ---------------------------------------------------------------------------
// transpose + convert: dst[n][k] = bf16(src[k][n]), 768x768
// ---------------------------------------------------------------------------
__global__ __launch_bounds__(256) void transpose_cvt_kernel(
    const float* __restrict__ src, __hip_bfloat16* __restrict__ dst) {
  __shared__ float tile[32][33];
  const int bx = blockIdx.x % 24;  // src col tile
  const int by = blockIdx.x / 24;  // src row tile
  const int tx = threadIdx.x & 31;
  const int ty = threadIdx.x >> 5;
#pragma unroll
  for (int i = 0; i < 32; i += 8)
    tile[ty + i][tx] = src[(size_t)(by * 32 + ty + i) * KD + bx * 32 + tx];
  __syncthreads();
#pragma unroll
  for (int i = 0; i < 32; i += 8)
    dst[(size_t)(bx * 32 + ty + i) * KD + by * 32 + tx] =
        __float2bfloat16(tile[tx][ty + i]);
}

// ---------------------------------------------------------------------------
// Conv / patch embedding (unchanged this round).
// emb[n,p,o] = sum_{i<16,k<3} cw[o,i,k] * xs[((p+k-1)&127)*8 + i]
// ---------------------------------------------------------------------------
__device__ __forceinline__ void load_patch(const float* __restrict__ xr,
                                           int qw, float* b) {
  if (qw < 127) {
    const float4* p4 = (const float4*)(xr + qw * 8);
    float4 v0 = p4[0], v1 = p4[1], v2 = p4[2], v3 = p4[3];
    b[0] = v0.x; b[1] = v0.y; b[2] = v0.z; b[3] = v0.w;
    b[4] = v1.x; b[5] = v1.y; b[6] = v1.z; b[7] = v1.w;
    b[8] = v2.x; b[9] = v2.y; b[10] = v2.z; b[11] = v2.w;
    b[12] = v3.x; b[13] = v3.y; b[14] = v3.z; b[15] = v3.w;
  } else {
    float4 v0 = *(const float4*)(xr + 1016);
    float4 v1 = *(const float4*)(xr + 1020);
    b[0] = v0.x; b[1] = v0.y; b[2] = v0.z; b[3] = v0.w;
    b[4] = v1.x; b[5] = v1.y; b[6] = v1.z; b[7] = v1.w;
    float e = v1.w;  // x[1023], edge value
#pragma unroll
    for (int i = 8; i < 16; ++i) b[i] = e;
  }
}

__global__ __launch_bounds__(256) void conv_kernel(
    const float* __restrict__ x, const float* __restrict__ cw,
    __hip_bfloat16* __restrict__ emb, int nb) {
  const int lb = blockIdx.x;       // chunk-local series index
  const int n = nb + lb;           // global series index (b*21+c)
  const float* xr = x + (size_t)n * 1024;
  const int o = blockIdx.y * 256 + threadIdx.x;

  float w[48];
  const float4* wp = (const float4*)(cw + (size_t)o * 48);
#pragma unroll
  for (int q = 0; q < 12; ++q) {
    float4 v = wp[q];
    w[q * 4 + 0] = v.x; w[q * 4 + 1] = v.y;
    w[q * 4 + 2] = v.z; w[q * 4 + 3] = v.w;
  }

  __hip_bfloat16* erow = emb + (size_t)lb * 128 * KD + o;
  float P0[16], P1[16], P2[16], P3[16];
  for (int p = 0; p < 128; p += 2) {
    load_patch(xr, (p + 127) & 127, P0);   // q = p-1 (wrap)
    load_patch(xr, p, P1);
    load_patch(xr, p + 1, P2);             // p+1 <= 127
    load_patch(xr, (p + 2) & 127, P3);     // q = p+2 (wrap)
    float a0 = 0.f, a1 = 0.f;
#pragma unroll
    for (int i = 0; i < 16; ++i) {
      a0 += w[i * 3 + 0] * P0[i];
      a0 += w[i * 3 + 1] * P1[i];
      a0 += w[i * 3 + 2] * P2[i];
      a1 += w[i * 3 + 0] * P1[i];
      a1 += w[i * 3 + 1] * P2[i];
      a1 += w[i * 3 + 2] * P3[i];
    }
    erow[(size_t)p * KD] = __float2bfloat16(a0);
    erow[(size_t)(p + 1) * KD] = __float2bfloat16(a1);
  }
}

// ---------------------------------------------------------------------------
// bf16 MFMA GEMM, 256x256 tile / BK=64 / 8 waves (2M x 4N), 512 threads.
// Each wave owns a 128x64 C tile = 8x4 fragments of 16x16x32 MFMA.
// LDS: 2 K-tile double buffer per operand, 2*2*256*64*2B = 128 KiB total.
// Row layout: 64 ushorts (8 chunks of 16B); chunk q of row r stored at slot
// q ^ (r&7)  -> ds_read_b128 across the wave hits every bank exactly 8x
// (the bandwidth floor; no conflict). global_load_lds has a linear lane-dest,
// so the swizzle is applied by inverse-permuting the per-lane GLOBAL source
// (rule: both-sides-or-neither).
// Pipeline (T4): counted s_waitcnt vmcnt(8) -- next K-tile's 8 loads stay in
// flight across both barriers while the current tile's 64 MFMA/wave run.
// T5: setprio(1) around each 32-MFMA cluster.
// MODE 1: out = bf16(relu(acc + bias))          (hidden, bf16*)
// MODE 2: out = float(emb) + acc + bias         (final,  float*)
// ---------------------------------------------------------------------------
template <int MODE>
__global__ __launch_bounds__(512, 2) void gemm_kernel(
    const __hip_bfloat16* __restrict__ A, const __hip_bfloat16* __restrict__ Bt,
    const float* __restrict__ bias, const __hip_bfloat16* __restrict__ emb,
    void* __restrict__ outp) {
  __shared__ __align__(16) ushort_t As[2 * 256 * 64];  // 64 KiB
  __shared__ __align__(16) ushort_t Bs[2 * 256 * 64];  // 64 KiB
  const int tid = threadIdx.x;
  const int lane = tid & 63;
  const int w = __builtin_amdgcn_readfirstlane(tid >> 6);  // wave id 0..7
  const int m0 = blockIdx.x * 256;
  const int n0 = blockIdx.y * 256;

  // ---- staging addresses (global side). Wave w stages rows w*32..w*32+31
  // of both tiles: 4 instrs x (8 rows x 128B) per operand per K-tile.
  const int sr = lane >> 3;            // row within 8-row slab (0..7)
  const int sc = (lane & 7) ^ sr;      // source k-chunk (inverse swizzle)
  const size_t ga = (size_t)(m0 + w * 32 + sr) * KD + sc * 8;
  const size_t gb = (size_t)(n0 + w * 32 + sr) * KD + sc * 8;
  typedef __attribute__((address_space(3))) void lv_t;
  typedef __attribute__((address_space(1))) const void gv_t;

  auto stage = [&](int kt, int b) {
#pragma unroll
    for (int i = 0; i < 4; ++i)
      __builtin_amdgcn_global_load_lds(
          (gv_t*)(A + ga + kt + (size_t)(i * 8) * KD),
          (lv_t*)((char*)&As[0] + b * 32768 + w * 4096 + i * 1024), 16, 0, 0);
#pragma unroll
    for (int i = 0; i < 4; ++i)
      __builtin_amdgcn_global_load_lds(
          (gv_t*)(Bt + gb + kt + (size_t)(i * 8) * KD),
          (lv_t*)((char*)&Bs[0] + b * 32768 + w * 4096 + i * 1024), 16, 0, 0);
  };

  // ---- compute-side LDS offsets ----
  const int rl = lane & 15;            // fragment row/col within 16
  const int ql = lane >> 4;            // k sub-chunk 0..3
  const int wm = (w >> 2) * 128;       // wave M offset
  const int wn = (w & 3) * 64;         // wave N offset
  const int so0 = (ql ^ (rl & 7)) * 8; // ks=0 swizzled chunk offset (ushorts)
  const int ra = (wm + rl) * 64;       // + mi*1024 per 16-row fragment
  const int rb = (wn + rl) * 64;       // + nj*1024

  floatx4 acc[8][4];
#pragma unroll
  for (int mi = 0; mi < 8; ++mi)
#pragma unroll
    for (int nj = 0; nj < 4; ++nj) acc[mi][nj] = (floatx4){0.f, 0.f, 0.f, 0.f};

  auto comp = [&](int b) {
    const ushort_t* Ab = &As[b * 16384];
    const ushort_t* Bb = &Bs[b * 16384];
#pragma unroll
    for (int ks = 0; ks < 2; ++ks) {
      const int so = so0 ^ (ks * 32);  // chunk 4+q = slot^(bit2): addr ^ 64B
      bf16x8 av[8], bv[4];
#pragma unroll
      for (int mi = 0; mi < 8; ++mi)
        av[mi] =
            __builtin_bit_cast(bf16x8, *(const ushort8*)&Ab[ra + mi * 1024 + so]);
#pragma unroll
      for (int nj = 0; nj < 4; ++nj)
        bv[nj] =
            __builtin_bit_cast(bf16x8, *(const ushort8*)&Bb[rb + nj * 1024 + so]);
      __builtin_amdgcn_s_setprio(1);
#pragma unroll
      for (int mi = 0; mi < 8; ++mi)
#pragma unroll
        for (int nj = 0; nj < 4; ++nj)
          acc[mi][nj] = __builtin_amdgcn_mfma_f32_16x16x32_bf16(
              av[mi], bv[nj], acc[mi][nj], 0, 0, 0);
      __builtin_amdgcn_s_setprio(0);
    }
  };

  // ---- main loop: 12 K-tiles, 2-deep staged, counted vmcnt ----
  stage(0, 0);
  stage(64, 1);
  for (int t = 0; t < 12; ++t) {
    // Wait tile t's 8 loads; leave tile t+1's 8 in flight across the barrier.
    if (t < 11)
      asm volatile("s_waitcnt vmcnt(8)\n\ts_barrier" ::: "memory");
    else
      asm volatile("s_waitcnt vmcnt(0)\n\ts_barrier" ::: "memory");
    comp(t & 1);
    // Drain own ds_reads, then rendezvous before anyone overwrites buf[t&1].
    asm volatile("s_waitcnt lgkmcnt(0)\n\ts_barrier" ::: "memory");
    if (t < 10) stage((t + 2) * 64, t & 1);
  }

  // ---- epilogue: D[row=(lane>>4)*4+p][col=lane&15] per 16x16 fragment ----
#pragma unroll
  for (int nj = 0; nj < 4; ++nj) {
    const int cc = n0 + wn + nj * 16 + rl;
    const float bvs = bias[cc];
#pragma unroll
    for (int mi = 0; mi < 8; ++mi) {
      const int rbase = m0 + wm + mi * 16 + ql * 4;
#pragma unroll
      for (int p = 0; p < 4; ++p) {
        float v = acc[mi][nj][p] + bvs;
        if (MODE == 1) {
          v = v > 0.f ? v : 0.f;
          ((__hip_bfloat16*)outp)[(size_t)(rbase + p) * KD + cc] =
              __float2bfloat16(v);
        } else {
          v += __bfloat162float(emb[(size_t)(rbase + p) * KD + cc]);
          ((float*)outp)[(size_t)(rbase + p) * KD + cc] = v;
        }
      }
    }
  }
}

// ---------------------------------------------------------------------------
extern "C" void kernel_launch(void* const* d_in, const int* in_sizes, int n_in,
                              void* d_out, int out_size, void* d_ws,
                              size_t ws_size, hipStream_t stream) {
  const float* x = (const float*)d_in[0];
  const float* cw = (const float*)d_in[1];
  const float* w1 = (const float*)d_in[2];
  const float* b1 = (const float*)d_in[3];
  const float* w2 = (const float*)d_in[4];
  const float* b2 = (const float*)d_in[5];
  // d_in[6] = reverse flag, unused by the reference computation.
  float* out = (float*)d_out;

  // Chunk the 1344 (b,c) series so emb/hidden bf16 intermediates fit d_ws
  // (and stay L3-resident). NC=4 -> ~134 MB of workspace. cn stays even,
  // so cn*128 is a multiple of 256 (GEMM BM).
  int NC = 4;
  while (NC < 32) {
    size_t cn_ = 1344 / NC;
    size_t need = 2 * (size_t)KD * KD * 2 + 2 * cn_ * 128 * KD * 2;
    if (need <= ws_size) break;
    NC *= 2;
  }
  const int cn = 1344 / NC;

  __hip_bfloat16* w1t = (__hip_bfloat16*)d_ws;
  __hip_bfloat16* w2t = w1t + (size_t)KD * KD;
  __hip_bfloat16* embc = w2t + (size_t)KD * KD;
  __hip_bfloat16* hidc = embc + (size_t)cn * 128 * KD;

  transpose_cvt_kernel<<<576, 256, 0, stream>>>(w1, w1t);
  transpose_cvt_kernel<<<576, 256, 0, stream>>>(w2, w2t);

  for (int c = 0; c < NC; ++c) {
    const int nb = c * cn;
    conv_kernel<<<dim3(cn, 3), 256, 0, stream>>>(x, cw, embc, nb);
    gemm_kernel<1><<<dim3(cn / 2, 3), 512, 0, stream>>>(embc, w1t, b1, nullptr,
                                                        (void*)hidc);
    gemm_kernel<2><<<dim3(cn / 2, 3), 512, 0, stream>>>(
        hidc, w2t, b2, embc, (void*)(out + (size_t)nb * 128 * KD));
  }
}